// Round 1
// baseline (580.121 us; speedup 1.0000x reference)
//
#include <hip/hip_runtime.h>

#define HH 56
#define WW2 56
#define WS 7
#define SHIFT 3
#define HEADS 4
#define DIM 128
#define NTOK 49
#define BATCH 64
#define TOKENS (BATCH*HH*WW2)   // 200704
#define NWIN 64                 // windows per image (8x8)
#define WINDOWS (BATCH*NWIN)    // 4096

typedef __bf16 bf16x8 __attribute__((ext_vector_type(8)));
typedef float  f32x4  __attribute__((ext_vector_type(4)));

__device__ __forceinline__ unsigned short f2bf(float f) {
  unsigned u = __float_as_uint(f);
  u += 0x7fffu + ((u >> 16) & 1u);
  return (unsigned short)(u >> 16);
}

// ---------------- weight prep: transpose + bf16 ----------------
__global__ __launch_bounds__(256) void k_prep(
    const float* __restrict__ qkv_w, const float* __restrict__ proj_w,
    const float* __restrict__ w1, const float* __restrict__ w2,
    unsigned short* __restrict__ qkvwT, unsigned short* __restrict__ projwT,
    unsigned short* __restrict__ w1T, unsigned short* __restrict__ w2T)
{
  int idx = blockIdx.x * 256 + threadIdx.x;
  if (idx < 49152) {                       // qkv_w [128][384] -> qkvwT [384][128]
    int n = idx >> 7, k = idx & 127;
    qkvwT[idx] = f2bf(qkv_w[k * 384 + n]);
  } else if (idx < 65536) {                // proj_w [128][128] -> projwT [128][128]
    int i = idx - 49152; int n = i >> 7, k = i & 127;
    projwT[i] = f2bf(proj_w[k * 128 + n]);
  } else if (idx < 131072) {               // mlp_w1 [128][512] -> w1T [512][128]
    int i = idx - 65536; int n = i >> 7, k = i & 127;
    w1T[i] = f2bf(w1[k * 512 + n]);
  } else {                                 // mlp_w2 [512][128] -> w2T [128][512]
    int i = idx - 131072; int n = i >> 9, k = i & 511;
    w2T[i] = f2bf(w2[k * 128 + n]);
  }
}

// ---------------- LN1 + cyclic shift + window partition ----------------
__global__ __launch_bounds__(256) void k_ln1_window(
    const float* __restrict__ x, const float* __restrict__ w,
    const float* __restrict__ b, unsigned short* __restrict__ xw)
{
  int lane = threadIdx.x & 63;
  int t = blockIdx.x * 4 + (threadIdx.x >> 6);
  const float* xp = x + (size_t)t * DIM;
  float2 v = *(const float2*)(xp + lane * 2);
  float s = v.x + v.y;
  float sq = v.x * v.x + v.y * v.y;
  #pragma unroll
  for (int off = 32; off; off >>= 1) {
    s += __shfl_xor(s, off);
    sq += __shfl_xor(sq, off);
  }
  float mean = s * (1.0f / DIM);
  float var = sq * (1.0f / DIM) - mean * mean;
  float rs = rsqrtf(var + 1e-5f);
  float2 wv = *(const float2*)(w + lane * 2);
  float2 bv = *(const float2*)(b + lane * 2);
  float y0 = (v.x - mean) * rs * wv.x + bv.x;
  float y1 = (v.y - mean) * rs * wv.y + bv.y;
  int bi = t / (HH * WW2);
  int r = t % (HH * WW2);
  int i = r / WW2, j = r % WW2;
  int si = i >= SHIFT ? i - SHIFT : i + (HH - SHIFT);
  int sj = j >= SHIFT ? j - SHIFT : j + (WW2 - SHIFT);
  int win = bi * NWIN + (si / WS) * 8 + (sj / WS);
  int tok = (si % WS) * WS + (sj % WS);
  unsigned pack = ((unsigned)f2bf(y1) << 16) | (unsigned)f2bf(y0);
  *(unsigned*)(xw + ((size_t)(win * NTOK + tok)) * DIM + lane * 2) = pack;
}

// ---------------- fused window attention ----------------
// one block = one window; 4 waves; wave h owns head h in phases 2/3
__device__ __forceinline__ int reg3(int g) { return g >= 53 ? 2 : (g >= 49 ? 1 : 0); }

__global__ __launch_bounds__(256) void k_attn(
    const unsigned short* __restrict__ xw,
    const unsigned short* __restrict__ qkvwT,
    const float* __restrict__ qkv_b,
    const unsigned short* __restrict__ projwT,
    const float* __restrict__ proj_b,
    const float* __restrict__ rpb,
    unsigned short* __restrict__ attn_out)
{
  // LDS: 17408 + 33792 + 18432 = 69632 B -> 2 blocks/CU
  __shared__ __align__(16) unsigned short s_x[64 * 136];   // xw tile; later reused as attn-out tile (s_o)
  __shared__ __align__(16) unsigned short s_qk[64 * 264];  // q cols 0-127, k cols 128-255; later P (head h at cols h*64..)
  __shared__ __align__(16) unsigned short s_vT[128 * 72];  // v transposed [d][m]; later proj-out staging

  int tid = threadIdx.x;
  int wave = tid >> 6;
  int lane = tid & 63;
  int l = lane & 15, g = lane >> 4;
  int win = blockIdx.x;
  int wi = (win & 63) >> 3, wj = win & 7;

  // ---- phase 0: load window tile, zero pad rows ----
  const unsigned short* xwin = xw + (size_t)win * (NTOK * DIM);
  for (int idx = tid; idx < NTOK * 16; idx += 256) {
    int row = idx >> 4, seg = idx & 15;
    *(uint4*)&s_x[row * 136 + seg * 8] = *(const uint4*)(xwin + row * DIM + seg * 8);
  }
  for (int idx = tid; idx < 15 * 17; idx += 256) {
    int row = 49 + idx / 17, seg = idx % 17;
    *(uint4*)&s_x[row * 136 + seg * 8] = make_uint4(0, 0, 0, 0);
  }
  __syncthreads();

  // ---- phase 1: QKV GEMM  [64,128] @ [128,384] ----
  #pragma unroll
  for (int nti = 0; nti < 6; ++nti) {
    int nt = wave * 6 + nti;
    int col = nt * 16 + l;
    bf16x8 bfrag[4];
    #pragma unroll
    for (int kk = 0; kk < 4; ++kk)
      bfrag[kk] = *(const bf16x8*)(qkvwT + col * DIM + kk * 32 + g * 8);
    float bias = qkv_b[col];
    f32x4 acc[4];
    #pragma unroll
    for (int mt = 0; mt < 4; ++mt) acc[mt] = (f32x4){0.f, 0.f, 0.f, 0.f};
    #pragma unroll
    for (int kk = 0; kk < 4; ++kk)
      #pragma unroll
      for (int mt = 0; mt < 4; ++mt) {
        bf16x8 a = *(const bf16x8*)&s_x[(mt * 16 + l) * 136 + kk * 32 + g * 8];
        acc[mt] = __builtin_amdgcn_mfma_f32_16x16x32_bf16(a, bfrag[kk], acc[mt], 0, 0, 0);
      }
    #pragma unroll
    for (int mt = 0; mt < 4; ++mt)
      #pragma unroll
      for (int rr = 0; rr < 4; ++rr) {
        int row = mt * 16 + g * 4 + rr;
        float val = acc[mt][rr] + bias;
        if (col < DIM) {
          s_qk[row * 264 + col] = f2bf(val * 0.17677669529663687f);  // q * hd^-0.5
        } else if (col < 2 * DIM) {
          s_qk[row * 264 + col] = f2bf(val);                          // k
        } else {
          s_vT[(col - 2 * DIM) * 72 + row] = f2bf(val);               // v transposed
        }
      }
  }
  __syncthreads();

  // ---- phase 2: scores + softmax (wave = head) ----
  int h = wave;
  bf16x8 qf[4], kf[4];
  #pragma unroll
  for (int mt = 0; mt < 4; ++mt)
    qf[mt] = *(const bf16x8*)&s_qk[(mt * 16 + l) * 264 + h * 32 + g * 8];
  #pragma unroll
  for (int nt = 0; nt < 4; ++nt)
    kf[nt] = *(const bf16x8*)&s_qk[(nt * 16 + l) * 264 + 128 + h * 32 + g * 8];
  __syncthreads();  // q/k reads done; s_qk can be overwritten by P below

  f32x4 sc[4][4];
  #pragma unroll
  for (int nt = 0; nt < 4; ++nt)
    #pragma unroll
    for (int mt = 0; mt < 4; ++mt)
      sc[mt][nt] = __builtin_amdgcn_mfma_f32_16x16x32_bf16(qf[mt], kf[nt], (f32x4){0.f,0.f,0.f,0.f}, 0, 0, 0);

  int kiv[4], kjv[4], ridk[4]; bool cok[4];
  #pragma unroll
  for (int nt = 0; nt < 4; ++nt) {
    int c = nt * 16 + l;
    cok[nt] = c < NTOK;
    int ki = c / 7, kj = c % 7;
    kiv[nt] = ki; kjv[nt] = kj;
    ridk[nt] = reg3(wi * 7 + ki) * 3 + reg3(wj * 7 + kj);
  }
  #pragma unroll
  for (int mt = 0; mt < 4; ++mt)
    #pragma unroll
    for (int rr = 0; rr < 4; ++rr) {
      int row = mt * 16 + g * 4 + rr;
      if (row < NTOK) {
        int qi = row / 7, qj = row % 7;
        int ridq = reg3(wi * 7 + qi) * 3 + reg3(wj * 7 + qj);
        #pragma unroll
        for (int nt = 0; nt < 4; ++nt) {
          if (cok[nt]) {
            float bb = rpb[((qi - kiv[nt] + 6) * 13 + (qj - kjv[nt] + 6)) * HEADS + h];
            sc[mt][nt][rr] += bb + (ridq != ridk[nt] ? -100.0f : 0.0f);
          } else sc[mt][nt][rr] = -3e38f;
        }
      } else {
        #pragma unroll
        for (int nt = 0; nt < 4; ++nt)
          if (!cok[nt]) sc[mt][nt][rr] = -3e38f;
      }
    }

  #pragma unroll
  for (int mt = 0; mt < 4; ++mt)
    #pragma unroll
    for (int rr = 0; rr < 4; ++rr) {
      float m = fmaxf(fmaxf(sc[mt][0][rr], sc[mt][1][rr]), fmaxf(sc[mt][2][rr], sc[mt][3][rr]));
      #pragma unroll
      for (int off = 8; off; off >>= 1) m = fmaxf(m, __shfl_xor(m, off));
      float e0 = __expf(sc[mt][0][rr] - m), e1 = __expf(sc[mt][1][rr] - m);
      float e2 = __expf(sc[mt][2][rr] - m), e3 = __expf(sc[mt][3][rr] - m);
      float ssum = (e0 + e1) + (e2 + e3);
      #pragma unroll
      for (int off = 8; off; off >>= 1) ssum += __shfl_xor(ssum, off);
      float inv = 1.0f / ssum;
      int row = mt * 16 + g * 4 + rr;
      s_qk[row * 264 + h * 64 +  0 + l] = f2bf(cok[0] ? e0 * inv : 0.0f);
      s_qk[row * 264 + h * 64 + 16 + l] = f2bf(cok[1] ? e1 * inv : 0.0f);
      s_qk[row * 264 + h * 64 + 32 + l] = f2bf(cok[2] ? e2 * inv : 0.0f);
      s_qk[row * 264 + h * 64 + 48 + l] = f2bf(cok[3] ? e3 * inv : 0.0f);
    }
  __syncthreads();

  // ---- phase 3: P @ V  -> s_o (= s_x region) ----
  bf16x8 pf[4][2];
  #pragma unroll
  for (int mt = 0; mt < 4; ++mt)
    #pragma unroll
    for (int kk = 0; kk < 2; ++kk)
      pf[mt][kk] = *(const bf16x8*)&s_qk[(mt * 16 + l) * 264 + h * 64 + kk * 32 + g * 8];
  #pragma unroll
  for (int nt = 0; nt < 2; ++nt) {
    bf16x8 b0 = *(const bf16x8*)&s_vT[(h * 32 + nt * 16 + l) * 72 + 0  + g * 8];
    bf16x8 b1 = *(const bf16x8*)&s_vT[(h * 32 + nt * 16 + l) * 72 + 32 + g * 8];
    #pragma unroll
    for (int mt = 0; mt < 4; ++mt) {
      f32x4 a = (f32x4){0.f,0.f,0.f,0.f};
      a = __builtin_amdgcn_mfma_f32_16x16x32_bf16(pf[mt][0], b0, a, 0, 0, 0);
      a = __builtin_amdgcn_mfma_f32_16x16x32_bf16(pf[mt][1], b1, a, 0, 0, 0);
      #pragma unroll
      for (int rr = 0; rr < 4; ++rr) {
        int row = mt * 16 + g * 4 + rr;
        s_x[row * 136 + h * 32 + nt * 16 + l] = f2bf(a[rr]);
      }
    }
  }
  __syncthreads();

  // ---- phase 4: proj GEMM [64,128]@[128,128] -> stage (s_vT region) ----
  unsigned short* stage = s_vT;
  #pragma unroll
  for (int nti = 0; nti < 2; ++nti) {
    int col = (wave * 2 + nti) * 16 + l;
    bf16x8 bfrag[4];
    #pragma unroll
    for (int kk = 0; kk < 4; ++kk)
      bfrag[kk] = *(const bf16x8*)(projwT + col * DIM + kk * 32 + g * 8);
    f32x4 acc[4];
    #pragma unroll
    for (int mt = 0; mt < 4; ++mt) acc[mt] = (f32x4){0.f,0.f,0.f,0.f};
    #pragma unroll
    for (int kk = 0; kk < 4; ++kk)
      #pragma unroll
      for (int mt = 0; mt < 4; ++mt) {
        bf16x8 a = *(const bf16x8*)&s_x[(mt * 16 + l) * 136 + kk * 32 + g * 8];
        acc[mt] = __builtin_amdgcn_mfma_f32_16x16x32_bf16(a, bfrag[kk], acc[mt], 0, 0, 0);
      }
    float pb = proj_b[col];
    #pragma unroll
    for (int mt = 0; mt < 4; ++mt)
      #pragma unroll
      for (int rr = 0; rr < 4; ++rr) {
        int row = mt * 16 + g * 4 + rr;
        if (row < NTOK) stage[row * DIM + col] = f2bf(acc[mt][rr] + pb);
      }
  }
  __syncthreads();

  unsigned short* outp = attn_out + (size_t)win * (NTOK * DIM);
  for (int idx = tid; idx < NTOK * 16; idx += 256)
    *(uint4*)(outp + idx * 8) = *(const uint4*)&stage[idx * 8];
}

// ---------------- residual + LN2 ----------------
__global__ __launch_bounds__(256) void k_resid_ln2(
    const float* __restrict__ x, const unsigned short* __restrict__ attn,
    const float* __restrict__ w, const float* __restrict__ b,
    float* __restrict__ x2, unsigned short* __restrict__ h2)
{
  int lane = threadIdx.x & 63;
  int t = blockIdx.x * 4 + (threadIdx.x >> 6);
  int bi = t / (HH * WW2);
  int r = t % (HH * WW2);
  int i = r / WW2, j = r % WW2;
  int si = i >= SHIFT ? i - SHIFT : i + (HH - SHIFT);
  int sj = j >= SHIFT ? j - SHIFT : j + (WW2 - SHIFT);
  int win = bi * NWIN + (si / WS) * 8 + (sj / WS);
  int tok = (si % WS) * WS + (sj % WS);
  float2 v = *(const float2*)(x + (size_t)t * DIM + lane * 2);
  unsigned ap = *(const unsigned*)(attn + ((size_t)(win * NTOK + tok)) * DIM + lane * 2);
  float z0 = v.x + __uint_as_float(ap << 16);
  float z1 = v.y + __uint_as_float(ap & 0xffff0000u);
  float s = z0 + z1;
  float sq = z0 * z0 + z1 * z1;
  #pragma unroll
  for (int off = 32; off; off >>= 1) {
    s += __shfl_xor(s, off);
    sq += __shfl_xor(sq, off);
  }
  float mean = s * (1.0f / DIM);
  float var = sq * (1.0f / DIM) - mean * mean;
  float rs = rsqrtf(var + 1e-5f);
  float2 wv = *(const float2*)(w + lane * 2);
  float2 bv = *(const float2*)(b + lane * 2);
  float y0 = (z0 - mean) * rs * wv.x + bv.x;
  float y1 = (z1 - mean) * rs * wv.y + bv.y;
  *(float2*)(x2 + (size_t)t * DIM + lane * 2) = make_float2(z0, z1);
  unsigned pack = ((unsigned)f2bf(y1) << 16) | (unsigned)f2bf(y0);
  *(unsigned*)(h2 + (size_t)t * DIM + lane * 2) = pack;
}

// ---------------- fused MLP: out = x2 + gelu(h2@w1+b1)@w2 + b2 ----------------
__global__ __launch_bounds__(256) void k_mlp(
    const unsigned short* __restrict__ h2,
    const unsigned short* __restrict__ w1T, const float* __restrict__ b1,
    const unsigned short* __restrict__ w2T, const float* __restrict__ b2,
    float* __restrict__ io)
{
  __shared__ __align__(16) unsigned short s_h[64 * 136];
  __shared__ __align__(16) unsigned short s_t[64 * 136];
  int tid = threadIdx.x;
  int wave = tid >> 6;
  int lane = tid & 63;
  int l = lane & 15, g = lane >> 4;
  size_t m0 = (size_t)blockIdx.x * 64;
  const unsigned short* hp = h2 + m0 * DIM;
  for (int idx = tid; idx < 64 * 16; idx += 256) {
    int row = idx >> 4, seg = idx & 15;
    *(uint4*)&s_h[row * 136 + seg * 8] = *(const uint4*)(hp + row * DIM + seg * 8);
  }
  __syncthreads();

  f32x4 o[4][2];
  #pragma unroll
  for (int mt = 0; mt < 4; ++mt)
    #pragma unroll
    for (int nti = 0; nti < 2; ++nti) o[mt][nti] = (f32x4){0.f,0.f,0.f,0.f};

  for (int c = 0; c < 4; ++c) {
    // GEMM1 chunk: t1 = gelu(h @ w1[:, c*128 .. +128))
    #pragma unroll
    for (int nti = 0; nti < 2; ++nti) {
      int ct = (wave * 2 + nti) * 16 + l;
      int n = c * 128 + ct;
      bf16x8 bfrag[4];
      #pragma unroll
      for (int kk = 0; kk < 4; ++kk)
        bfrag[kk] = *(const bf16x8*)(w1T + (size_t)n * DIM + kk * 32 + g * 8);
      f32x4 acc[4];
      #pragma unroll
      for (int mt = 0; mt < 4; ++mt) acc[mt] = (f32x4){0.f,0.f,0.f,0.f};
      #pragma unroll
      for (int kk = 0; kk < 4; ++kk)
        #pragma unroll
        for (int mt = 0; mt < 4; ++mt) {
          bf16x8 a = *(const bf16x8*)&s_h[(mt * 16 + l) * 136 + kk * 32 + g * 8];
          acc[mt] = __builtin_amdgcn_mfma_f32_16x16x32_bf16(a, bfrag[kk], acc[mt], 0, 0, 0);
        }
      float bias = b1[n];
      #pragma unroll
      for (int mt = 0; mt < 4; ++mt)
        #pragma unroll
        for (int rr = 0; rr < 4; ++rr) {
          int row = mt * 16 + g * 4 + rr;
          float v = acc[mt][rr] + bias;
          v = 0.5f * v * (1.0f + erff(v * 0.70710678118654752f));
          s_t[row * 136 + ct] = f2bf(v);
        }
    }
    __syncthreads();
    // GEMM2 chunk: o += t1 @ w2[c*128 .. +128, :]
    #pragma unroll
    for (int nti = 0; nti < 2; ++nti) {
      int col = (wave * 2 + nti) * 16 + l;
      bf16x8 bfrag[4];
      #pragma unroll
      for (int kk = 0; kk < 4; ++kk)
        bfrag[kk] = *(const bf16x8*)(w2T + (size_t)col * 512 + c * 128 + kk * 32 + g * 8);
      #pragma unroll
      for (int kk = 0; kk < 4; ++kk)
        #pragma unroll
        for (int mt = 0; mt < 4; ++mt) {
          bf16x8 a = *(const bf16x8*)&s_t[(mt * 16 + l) * 136 + kk * 32 + g * 8];
          o[mt][nti] = __builtin_amdgcn_mfma_f32_16x16x32_bf16(a, bfrag[kk], o[mt][nti], 0, 0, 0);
        }
    }
    __syncthreads();
  }

  #pragma unroll
  for (int nti = 0; nti < 2; ++nti) {
    int col = (wave * 2 + nti) * 16 + l;
    float bias = b2[col];
    #pragma unroll
    for (int mt = 0; mt < 4; ++mt)
      #pragma unroll
      for (int rr = 0; rr < 4; ++rr) {
        int row = mt * 16 + g * 4 + rr;
        float* p = io + (m0 + row) * DIM + col;
        *p = *p + o[mt][nti][rr] + bias;
      }
  }
}

extern "C" void kernel_launch(void* const* d_in, const int* in_sizes, int n_in,
                              void* d_out, int out_size, void* d_ws, size_t ws_size,
                              hipStream_t stream) {
  const float* x       = (const float*)d_in[0];
  const float* qkv_w   = (const float*)d_in[1];
  const float* qkv_b   = (const float*)d_in[2];
  const float* proj_w  = (const float*)d_in[3];
  const float* proj_b  = (const float*)d_in[4];
  const float* rpb     = (const float*)d_in[5];
  const float* n1w     = (const float*)d_in[6];
  const float* n1b     = (const float*)d_in[7];
  const float* n2w     = (const float*)d_in[8];
  const float* n2b     = (const float*)d_in[9];
  const float* mlp_w1  = (const float*)d_in[10];
  const float* mlp_b1  = (const float*)d_in[11];
  const float* mlp_w2  = (const float*)d_in[12];
  const float* mlp_b2  = (const float*)d_in[13];
  float* out = (float*)d_out;

  char* ws = (char*)d_ws;
  const size_t TOKB = (size_t)TOKENS * DIM * 2;     // 51,380,224 B
  unsigned short* xw     = (unsigned short*)(ws);            // also h2 (aliased; xw dead by then)
  unsigned short* attn_o = (unsigned short*)(ws + TOKB);
  unsigned short* qkvwT  = (unsigned short*)(ws + 2 * TOKB);
  unsigned short* projwT = (unsigned short*)(ws + 2 * TOKB + 98304);
  unsigned short* w1T    = (unsigned short*)(ws + 2 * TOKB + 98304 + 32768);
  unsigned short* w2T    = (unsigned short*)(ws + 2 * TOKB + 98304 + 32768 + 131072);
  unsigned short* h2     = xw;

  k_prep<<<768, 256, 0, stream>>>(qkv_w, proj_w, mlp_w1, mlp_w2, qkvwT, projwT, w1T, w2T);
  k_ln1_window<<<TOKENS / 4, 256, 0, stream>>>(x, n1w, n1b, xw);
  k_attn<<<WINDOWS, 256, 0, stream>>>(xw, qkvwT, qkv_b, projwT, proj_b, rpb, attn_o);
  k_resid_ln2<<<TOKENS / 4, 256, 0, stream>>>(x, attn_o, n2w, n2b, out, h2);
  k_mlp<<<TOKENS / 64, 256, 0, stream>>>(h2, w1T, mlp_b1, w2T, mlp_b2, out);
}

// Round 2
// 560.332 us; speedup vs baseline: 1.0353x; 1.0353x over previous
//
#include <hip/hip_runtime.h>

#define HH 56
#define WW2 56
#define WS 7
#define SHIFT 3
#define HEADS 4
#define DIM 128
#define NTOK 49
#define BATCH 64
#define TOKENS (BATCH*HH*WW2)   // 200704
#define NWIN 64                 // windows per image (8x8)
#define WINDOWS (BATCH*NWIN)    // 4096

typedef __bf16 bf16x8 __attribute__((ext_vector_type(8)));
typedef float  f32x4  __attribute__((ext_vector_type(4)));

__device__ __forceinline__ unsigned short f2bf(float f) {
  unsigned u = __float_as_uint(f);
  u += 0x7fffu + ((u >> 16) & 1u);
  return (unsigned short)(u >> 16);
}

__device__ __forceinline__ void st4(unsigned short* p, float a, float b, float c, float d) {
  ushort4 pk; pk.x = f2bf(a); pk.y = f2bf(b); pk.z = f2bf(c); pk.w = f2bf(d);
  *(ushort4*)p = pk;
}

__device__ __forceinline__ int reg3(int g) { return g >= 53 ? 2 : (g >= 49 ? 1 : 0); }

// ---------------- weight prep: transpose + bf16 ----------------
__global__ __launch_bounds__(256) void k_prep(
    const float* __restrict__ qkv_w, const float* __restrict__ proj_w,
    const float* __restrict__ w1, const float* __restrict__ w2,
    unsigned short* __restrict__ qkvwT, unsigned short* __restrict__ projwT,
    unsigned short* __restrict__ w1T, unsigned short* __restrict__ w2T)
{
  int idx = blockIdx.x * 256 + threadIdx.x;
  if (idx < 49152) {                       // qkv_w [128][384] -> qkvwT [384][128]
    int n = idx >> 7, k = idx & 127;
    qkvwT[idx] = f2bf(qkv_w[k * 384 + n]);
  } else if (idx < 65536) {                // proj_w [128][128] -> projwT [128][128]
    int i = idx - 49152; int n = i >> 7, k = i & 127;
    projwT[i] = f2bf(proj_w[k * 128 + n]);
  } else if (idx < 131072) {               // mlp_w1 [128][512] -> w1T [512][128]
    int i = idx - 65536; int n = i >> 7, k = i & 127;
    w1T[i] = f2bf(w1[k * 512 + n]);
  } else {                                 // mlp_w2 [512][128] -> w2T [128][512]
    int i = idx - 131072; int n = i >> 9, k = i & 511;
    w2T[i] = f2bf(w2[k * 128 + n]);
  }
}

// ---------------- bias+mask table: [cls][head][qtoken 64][ktoken 64] fp32 ----------------
__global__ __launch_bounds__(256) void k_tbl(const float* __restrict__ rpb, float* __restrict__ tbl)
{
  int idx = blockIdx.x * 256 + threadIdx.x;   // 65536 entries
  int kt = idx & 63, qt = (idx >> 6) & 63, h = (idx >> 12) & 3, cls = idx >> 14;
  float v;
  if (qt >= NTOK || kt >= NTOK) v = -3e38f;
  else {
    int qi = qt / 7, qj = qt % 7, ki = kt / 7, kj = kt % 7;
    int bi = (cls & 2) ? 49 : 0, bj = (cls & 1) ? 49 : 0;
    int rq = reg3(bi + qi) * 3 + reg3(bj + qj);
    int rk = reg3(bi + ki) * 3 + reg3(bj + kj);
    v = rpb[((qi - ki + 6) * 13 + (qj - kj + 6)) * HEADS + h] + (rq != rk ? -100.0f : 0.0f);
  }
  tbl[idx] = v;
}

// ---------------- LN1 + cyclic shift + window partition ----------------
__global__ __launch_bounds__(256) void k_ln1_window(
    const float* __restrict__ x, const float* __restrict__ w,
    const float* __restrict__ b, unsigned short* __restrict__ xw)
{
  int lane = threadIdx.x & 63;
  int t = blockIdx.x * 4 + (threadIdx.x >> 6);
  const float* xp = x + (size_t)t * DIM;
  float2 v = *(const float2*)(xp + lane * 2);
  float s = v.x + v.y;
  float sq = v.x * v.x + v.y * v.y;
  #pragma unroll
  for (int off = 32; off; off >>= 1) {
    s += __shfl_xor(s, off);
    sq += __shfl_xor(sq, off);
  }
  float mean = s * (1.0f / DIM);
  float var = sq * (1.0f / DIM) - mean * mean;
  float rs = rsqrtf(var + 1e-5f);
  float2 wv = *(const float2*)(w + lane * 2);
  float2 bv = *(const float2*)(b + lane * 2);
  float y0 = (v.x - mean) * rs * wv.x + bv.x;
  float y1 = (v.y - mean) * rs * wv.y + bv.y;
  int bi = t / (HH * WW2);
  int r = t % (HH * WW2);
  int i = r / WW2, j = r % WW2;
  int si = i >= SHIFT ? i - SHIFT : i + (HH - SHIFT);
  int sj = j >= SHIFT ? j - SHIFT : j + (WW2 - SHIFT);
  int win = bi * NWIN + (si / WS) * 8 + (sj / WS);
  int tok = (si % WS) * WS + (sj % WS);
  unsigned pack = ((unsigned)f2bf(y1) << 16) | (unsigned)f2bf(y0);
  *(unsigned*)(xw + ((size_t)(win * NTOK + tok)) * DIM + lane * 2) = pack;
}

// ---------------- fused window attention (transposed-output GEMMs) ----------------
__global__ __launch_bounds__(256, 2) void k_attn(
    const unsigned short* __restrict__ xw,
    const unsigned short* __restrict__ qkvwT,
    const float* __restrict__ qkv_b,
    const unsigned short* __restrict__ projwT,
    const float* __restrict__ proj_b,
    const float* __restrict__ tbl,
    unsigned short* __restrict__ attn_out)
{
  // LDS: 17408 + 33792 + 18432 = 69632 B -> 2 blocks/CU
  __shared__ __align__(16) unsigned short s_x[64 * 136];   // x tile; then PV [token][d]
  __shared__ __align__(16) unsigned short s_qk[64 * 264];  // q|k [token][dim]; then P [qtok][ktok] per head
  __shared__ __align__(16) unsigned short s_vT[128 * 72];  // v^T [d][token]; then proj-out stage

  int tid = threadIdx.x;
  int wave = tid >> 6;
  int lane = tid & 63;
  int l = lane & 15, g = lane >> 4;
  int win = blockIdx.x;
  int wi = (win & 63) >> 3, wj = win & 7;

  // ---- phase 0: load window tile, zero pad rows ----
  const unsigned short* xwin = xw + (size_t)win * (NTOK * DIM);
  for (int idx = tid; idx < NTOK * 16; idx += 256) {
    int row = idx >> 4, seg = idx & 15;
    *(uint4*)&s_x[row * 136 + seg * 8] = *(const uint4*)(xwin + row * DIM + seg * 8);
  }
  for (int idx = tid; idx < 15 * 17; idx += 256) {
    int row = 49 + idx / 17, seg = idx % 17;
    *(uint4*)&s_x[row * 136 + seg * 8] = make_uint4(0, 0, 0, 0);
  }
  __syncthreads();

  // ---- phase 1: QKV^T GEMM: A=weights [wcol][k], B=x [token][k], D=[wcol][token] ----
  bf16x8 xf[4][4];   // [nt(token tile)][kk]
  #pragma unroll
  for (int nt = 0; nt < 4; ++nt)
    #pragma unroll
    for (int kk = 0; kk < 4; ++kk)
      xf[nt][kk] = *(const bf16x8*)&s_x[(nt * 16 + l) * 136 + kk * 32 + g * 8];

  #pragma unroll
  for (int wti = 0; wti < 6; ++wti) {
    int wt = wave * 6 + wti;                 // m-tile over 384 wcols
    bf16x8 wf[4];
    #pragma unroll
    for (int kk = 0; kk < 4; ++kk)
      wf[kk] = *(const bf16x8*)(qkvwT + (size_t)(wt * 16 + l) * DIM + kk * 32 + g * 8);
    f32x4 acc[4];
    #pragma unroll
    for (int nt = 0; nt < 4; ++nt) acc[nt] = (f32x4){0.f, 0.f, 0.f, 0.f};
    #pragma unroll
    for (int kk = 0; kk < 4; ++kk)
      #pragma unroll
      for (int nt = 0; nt < 4; ++nt)
        acc[nt] = __builtin_amdgcn_mfma_f32_16x16x32_bf16(wf[kk], xf[nt][kk], acc[nt], 0, 0, 0);
    float4 b4 = *(const float4*)(qkv_b + wt * 16 + g * 4);
    if (wt < 16) {           // q (wt<8, cols 0-127) and k (cols 128-255): col = wt*16+g*4
      float sc = wt < 8 ? 0.17677669529663687f : 1.0f;
      #pragma unroll
      for (int nt = 0; nt < 4; ++nt)
        st4(&s_qk[(nt * 16 + l) * 264 + wt * 16 + g * 4],
            (acc[nt][0] + b4.x) * sc, (acc[nt][1] + b4.y) * sc,
            (acc[nt][2] + b4.z) * sc, (acc[nt][3] + b4.w) * sc);
    } else {                 // v -> v^T [d][token]
      int d0 = wt * 16 - 256 + g * 4;
      #pragma unroll
      for (int nt = 0; nt < 4; ++nt) {
        s_vT[(d0 + 0) * 72 + nt * 16 + l] = f2bf(acc[nt][0] + b4.x);
        s_vT[(d0 + 1) * 72 + nt * 16 + l] = f2bf(acc[nt][1] + b4.y);
        s_vT[(d0 + 2) * 72 + nt * 16 + l] = f2bf(acc[nt][2] + b4.z);
        s_vT[(d0 + 3) * 72 + nt * 16 + l] = f2bf(acc[nt][3] + b4.w);
      }
    }
  }
  __syncthreads();

  // ---- phase 2: S^T = K.Q^T with table C-init; in-register softmax; P [qtok][ktok] ----
  int h = wave;
  bf16x8 kf[4], qf[4];
  #pragma unroll
  for (int mt = 0; mt < 4; ++mt)
    kf[mt] = *(const bf16x8*)&s_qk[(mt * 16 + l) * 264 + 128 + h * 32 + g * 8];
  #pragma unroll
  for (int nt = 0; nt < 4; ++nt)
    qf[nt] = *(const bf16x8*)&s_qk[(nt * 16 + l) * 264 + h * 32 + g * 8];
  __syncthreads();   // all q/k fragment reads done; s_qk reusable as P

  int clsid = ((wi == 7) ? 2 : 0) | ((wj == 7) ? 1 : 0);
  const float* tb = tbl + ((clsid * 4 + h) << 12);
  f32x4 sc[4][4];    // [mt=ktok tile][nt=qtok tile]
  #pragma unroll
  for (int nt = 0; nt < 4; ++nt)
    #pragma unroll
    for (int mt = 0; mt < 4; ++mt) {
      f32x4 ci = *(const f32x4*)(tb + (nt * 16 + l) * 64 + mt * 16 + g * 4);
      sc[mt][nt] = __builtin_amdgcn_mfma_f32_16x16x32_bf16(kf[mt], qf[nt], ci, 0, 0, 0);
    }

  #pragma unroll
  for (int nt = 0; nt < 4; ++nt) {
    float m = sc[0][nt][0];
    #pragma unroll
    for (int mt = 0; mt < 4; ++mt)
      #pragma unroll
      for (int rr = 0; rr < 4; ++rr) m = fmaxf(m, sc[mt][nt][rr]);
    m = fmaxf(m, __shfl_xor(m, 16));
    m = fmaxf(m, __shfl_xor(m, 32));
    float ssum = 0.f;
    #pragma unroll
    for (int mt = 0; mt < 4; ++mt)
      #pragma unroll
      for (int rr = 0; rr < 4; ++rr) {
        float e = __expf(sc[mt][nt][rr] - m);
        sc[mt][nt][rr] = e;
        ssum += e;
      }
    ssum += __shfl_xor(ssum, 16);
    ssum += __shfl_xor(ssum, 32);
    float inv = 1.0f / ssum;
    #pragma unroll
    for (int mt = 0; mt < 4; ++mt)
      st4(&s_qk[(nt * 16 + l) * 264 + h * 64 + mt * 16 + g * 4],
          sc[mt][nt][0] * inv, sc[mt][nt][1] * inv, sc[mt][nt][2] * inv, sc[mt][nt][3] * inv);
  }
  // P write->read is same-wave; compiler orders via lgkmcnt. No barrier needed.

  // ---- phase 3: PV^T: A=v^T [d][ktok], B=P [qtok][ktok], D=[d][qtok] -> s_x[token][d] ----
  bf16x8 vf[2][2], pf[4][2];
  #pragma unroll
  for (int dt = 0; dt < 2; ++dt)
    #pragma unroll
    for (int kk = 0; kk < 2; ++kk)
      vf[dt][kk] = *(const bf16x8*)&s_vT[(h * 32 + dt * 16 + l) * 72 + kk * 32 + g * 8];
  #pragma unroll
  for (int nt = 0; nt < 4; ++nt)
    #pragma unroll
    for (int kk = 0; kk < 2; ++kk)
      pf[nt][kk] = *(const bf16x8*)&s_qk[(nt * 16 + l) * 264 + h * 64 + kk * 32 + g * 8];
  #pragma unroll
  for (int dt = 0; dt < 2; ++dt)
    #pragma unroll
    for (int nt = 0; nt < 4; ++nt) {
      f32x4 a = (f32x4){0.f, 0.f, 0.f, 0.f};
      a = __builtin_amdgcn_mfma_f32_16x16x32_bf16(vf[dt][0], pf[nt][0], a, 0, 0, 0);
      a = __builtin_amdgcn_mfma_f32_16x16x32_bf16(vf[dt][1], pf[nt][1], a, 0, 0, 0);
      st4(&s_x[(nt * 16 + l) * 136 + h * 32 + dt * 16 + g * 4], a[0], a[1], a[2], a[3]);
    }
  __syncthreads();

  // ---- phase 4: proj^T: A=projW^T [pcol][d], B=PV [token][d], D=[pcol][token] ----
  unsigned short* stage = s_vT;   // 64x136 fits in 128x72 region
  bf16x8 of[4][4];
  #pragma unroll
  for (int nt = 0; nt < 4; ++nt)
    #pragma unroll
    for (int kk = 0; kk < 4; ++kk)
      of[nt][kk] = *(const bf16x8*)&s_x[(nt * 16 + l) * 136 + kk * 32 + g * 8];
  #pragma unroll
  for (int wti = 0; wti < 2; ++wti) {
    int wt = wave * 2 + wti;
    bf16x8 wf[4];
    #pragma unroll
    for (int kk = 0; kk < 4; ++kk)
      wf[kk] = *(const bf16x8*)(projwT + (size_t)(wt * 16 + l) * DIM + kk * 32 + g * 8);
    f32x4 acc[4];
    #pragma unroll
    for (int nt = 0; nt < 4; ++nt) acc[nt] = (f32x4){0.f, 0.f, 0.f, 0.f};
    #pragma unroll
    for (int kk = 0; kk < 4; ++kk)
      #pragma unroll
      for (int nt = 0; nt < 4; ++nt)
        acc[nt] = __builtin_amdgcn_mfma_f32_16x16x32_bf16(wf[kk], of[nt][kk], acc[nt], 0, 0, 0);
    float4 b4 = *(const float4*)(proj_b + wt * 16 + g * 4);
    #pragma unroll
    for (int nt = 0; nt < 4; ++nt)
      st4(&stage[(nt * 16 + l) * 136 + wt * 16 + g * 4],
          acc[nt][0] + b4.x, acc[nt][1] + b4.y, acc[nt][2] + b4.z, acc[nt][3] + b4.w);
  }
  __syncthreads();

  unsigned short* outp = attn_out + (size_t)win * (NTOK * DIM);
  for (int idx = tid; idx < NTOK * 16; idx += 256) {
    int row = idx >> 4, seg = idx & 15;
    *(uint4*)(outp + idx * 8) = *(const uint4*)&stage[row * 136 + seg * 8];
  }
}

// ---------------- residual + LN2 ----------------
__global__ __launch_bounds__(256) void k_resid_ln2(
    const float* __restrict__ x, const unsigned short* __restrict__ attn,
    const float* __restrict__ w, const float* __restrict__ b,
    float* __restrict__ x2, unsigned short* __restrict__ h2)
{
  int lane = threadIdx.x & 63;
  int t = blockIdx.x * 4 + (threadIdx.x >> 6);
  int bi = t / (HH * WW2);
  int r = t % (HH * WW2);
  int i = r / WW2, j = r % WW2;
  int si = i >= SHIFT ? i - SHIFT : i + (HH - SHIFT);
  int sj = j >= SHIFT ? j - SHIFT : j + (WW2 - SHIFT);
  int win = bi * NWIN + (si / WS) * 8 + (sj / WS);
  int tok = (si % WS) * WS + (sj % WS);
  float2 v = *(const float2*)(x + (size_t)t * DIM + lane * 2);
  unsigned ap = *(const unsigned*)(attn + ((size_t)(win * NTOK + tok)) * DIM + lane * 2);
  float z0 = v.x + __uint_as_float(ap << 16);
  float z1 = v.y + __uint_as_float(ap & 0xffff0000u);
  float s = z0 + z1;
  float sq = z0 * z0 + z1 * z1;
  #pragma unroll
  for (int off = 32; off; off >>= 1) {
    s += __shfl_xor(s, off);
    sq += __shfl_xor(sq, off);
  }
  float mean = s * (1.0f / DIM);
  float var = sq * (1.0f / DIM) - mean * mean;
  float rs = rsqrtf(var + 1e-5f);
  float2 wv = *(const float2*)(w + lane * 2);
  float2 bv = *(const float2*)(b + lane * 2);
  float y0 = (z0 - mean) * rs * wv.x + bv.x;
  float y1 = (z1 - mean) * rs * wv.y + bv.y;
  *(float2*)(x2 + (size_t)t * DIM + lane * 2) = make_float2(z0, z1);
  unsigned pack = ((unsigned)f2bf(y1) << 16) | (unsigned)f2bf(y0);
  *(unsigned*)(h2 + (size_t)t * DIM + lane * 2) = pack;
}

__device__ __forceinline__ float gelu_f(float x) {
  float y = 0.7978845608028654f * x * (1.0f + 0.044715f * x * x);
  float e = __expf(-2.0f * fabsf(y));
  float t = __fdividef(1.0f - e, 1.0f + e);
  t = copysignf(t, y);
  return 0.5f * x * (1.0f + t);
}

// ---------------- fused MLP: out = x2 + gelu(h2@w1+b1)@w2 + b2 ----------------
__global__ __launch_bounds__(256) void k_mlp(
    const unsigned short* __restrict__ h2,
    const unsigned short* __restrict__ w1T, const float* __restrict__ b1,
    const unsigned short* __restrict__ w2T, const float* __restrict__ b2,
    float* __restrict__ io)
{
  __shared__ __align__(16) unsigned short s_h[64 * 136];
  __shared__ __align__(16) unsigned short s_t[64 * 136];
  int tid = threadIdx.x;
  int wave = tid >> 6;
  int lane = tid & 63;
  int l = lane & 15, g = lane >> 4;
  size_t m0 = (size_t)blockIdx.x * 64;
  const unsigned short* hp = h2 + m0 * DIM;
  for (int idx = tid; idx < 64 * 16; idx += 256) {
    int row = idx >> 4, seg = idx & 15;
    *(uint4*)&s_h[row * 136 + seg * 8] = *(const uint4*)(hp + row * DIM + seg * 8);
  }
  __syncthreads();

  bf16x8 hf[4][4];
  #pragma unroll
  for (int nt = 0; nt < 4; ++nt)
    #pragma unroll
    for (int kk = 0; kk < 4; ++kk)
      hf[nt][kk] = *(const bf16x8*)&s_h[(nt * 16 + l) * 136 + kk * 32 + g * 8];

  f32x4 o[2][4];
  #pragma unroll
  for (int wti = 0; wti < 2; ++wti)
    #pragma unroll
    for (int nt = 0; nt < 4; ++nt) o[wti][nt] = (f32x4){0.f, 0.f, 0.f, 0.f};

  for (int c = 0; c < 4; ++c) {
    // GEMM1^T chunk: D[w1col][token], gelu, store s_t[token][w1col-local]
    #pragma unroll
    for (int wti = 0; wti < 2; ++wti) {
      int wt = wave * 2 + wti;
      int n0 = c * 128 + wt * 16;
      bf16x8 wf[4];
      #pragma unroll
      for (int kk = 0; kk < 4; ++kk)
        wf[kk] = *(const bf16x8*)(w1T + (size_t)(n0 + l) * DIM + kk * 32 + g * 8);
      f32x4 acc[4];
      #pragma unroll
      for (int nt = 0; nt < 4; ++nt) acc[nt] = (f32x4){0.f, 0.f, 0.f, 0.f};
      #pragma unroll
      for (int kk = 0; kk < 4; ++kk)
        #pragma unroll
        for (int nt = 0; nt < 4; ++nt)
          acc[nt] = __builtin_amdgcn_mfma_f32_16x16x32_bf16(wf[kk], hf[nt][kk], acc[nt], 0, 0, 0);
      float4 b4 = *(const float4*)(b1 + n0 + g * 4);
      #pragma unroll
      for (int nt = 0; nt < 4; ++nt)
        st4(&s_t[(nt * 16 + l) * 136 + wt * 16 + g * 4],
            gelu_f(acc[nt][0] + b4.x), gelu_f(acc[nt][1] + b4.y),
            gelu_f(acc[nt][2] + b4.z), gelu_f(acc[nt][3] + b4.w));
    }
    __syncthreads();
    // GEMM2^T chunk: o[pcol][token] += w2 chunk . t chunk
    #pragma unroll
    for (int kk = 0; kk < 4; ++kk) {
      bf16x8 tf[4];
      #pragma unroll
      for (int nt = 0; nt < 4; ++nt)
        tf[nt] = *(const bf16x8*)&s_t[(nt * 16 + l) * 136 + kk * 32 + g * 8];
      #pragma unroll
      for (int wti = 0; wti < 2; ++wti) {
        int wt = wave * 2 + wti;
        bf16x8 wf2 = *(const bf16x8*)(w2T + (size_t)(wt * 16 + l) * 512 + c * 128 + kk * 32 + g * 8);
        #pragma unroll
        for (int nt = 0; nt < 4; ++nt)
          o[wti][nt] = __builtin_amdgcn_mfma_f32_16x16x32_bf16(wf2, tf[nt], o[wti][nt], 0, 0, 0);
      }
    }
    __syncthreads();
  }

  #pragma unroll
  for (int wti = 0; wti < 2; ++wti) {
    int wt = wave * 2 + wti;
    float4 b4 = *(const float4*)(b2 + wt * 16 + g * 4);
    #pragma unroll
    for (int nt = 0; nt < 4; ++nt) {
      float* p = io + (m0 + nt * 16 + l) * DIM + wt * 16 + g * 4;
      float4 pv = *(float4*)p;
      pv.x += o[wti][nt][0] + b4.x;
      pv.y += o[wti][nt][1] + b4.y;
      pv.z += o[wti][nt][2] + b4.z;
      pv.w += o[wti][nt][3] + b4.w;
      *(float4*)p = pv;
    }
  }
}

extern "C" void kernel_launch(void* const* d_in, const int* in_sizes, int n_in,
                              void* d_out, int out_size, void* d_ws, size_t ws_size,
                              hipStream_t stream) {
  const float* x       = (const float*)d_in[0];
  const float* qkv_w   = (const float*)d_in[1];
  const float* qkv_b   = (const float*)d_in[2];
  const float* proj_w  = (const float*)d_in[3];
  const float* proj_b  = (const float*)d_in[4];
  const float* rpb     = (const float*)d_in[5];
  const float* n1w     = (const float*)d_in[6];
  const float* n1b     = (const float*)d_in[7];
  const float* n2w     = (const float*)d_in[8];
  const float* n2b     = (const float*)d_in[9];
  const float* mlp_w1  = (const float*)d_in[10];
  const float* mlp_b1  = (const float*)d_in[11];
  const float* mlp_w2  = (const float*)d_in[12];
  const float* mlp_b2  = (const float*)d_in[13];
  float* out = (float*)d_out;

  char* ws = (char*)d_ws;
  const size_t TOKB = (size_t)TOKENS * DIM * 2;     // 51,380,224 B
  unsigned short* xw     = (unsigned short*)(ws);            // also h2 (aliased; xw dead by then)
  unsigned short* attn_o = (unsigned short*)(ws + TOKB);
  unsigned short* qkvwT  = (unsigned short*)(ws + 2 * TOKB);
  unsigned short* projwT = (unsigned short*)(ws + 2 * TOKB + 98304);
  unsigned short* w1T    = (unsigned short*)(ws + 2 * TOKB + 98304 + 32768);
  unsigned short* w2T    = (unsigned short*)(ws + 2 * TOKB + 98304 + 32768 + 131072);
  float*          tbl    = (float*)(ws + 2 * TOKB + 98304 + 32768 + 131072 + 131072);  // 262144 B
  unsigned short* h2     = xw;

  k_prep<<<768, 256, 0, stream>>>(qkv_w, proj_w, mlp_w1, mlp_w2, qkvwT, projwT, w1T, w2T);
  k_tbl<<<256, 256, 0, stream>>>(rpb, tbl);
  k_ln1_window<<<TOKENS / 4, 256, 0, stream>>>(x, n1w, n1b, xw);
  k_attn<<<WINDOWS, 256, 0, stream>>>(xw, qkvwT, qkv_b, projwT, proj_b, tbl, attn_o);
  k_resid_ln2<<<TOKENS / 4, 256, 0, stream>>>(x, attn_o, n2w, n2b, out, h2);
  k_mlp<<<TOKENS / 64, 256, 0, stream>>>(h2, w1T, mlp_b1, w2T, mlp_b2, out);
}